// Round 5
// baseline (9433.043 us; speedup 1.0000x reference)
//
#include <hip/hip_runtime.h>

#define T_TOK 1024
#define HID 2880
#define NH 64
#define KV 8
#define HD 64
#define INTER 2880
#define QKV_DIM 5120   // HD*(NH+2*KV)
#define O_DIM 4096     // NH*HD

// ---------------- RMSNorm (naive scalar, f32) ------------------------------
__global__ __launch_bounds__(256) void rmsnorm_naive(
    const float* __restrict__ x, const float* __restrict__ scale,
    float* __restrict__ out)
{
    const int row = blockIdx.x;
    const int tid = threadIdx.x;
    const float* xr = x + (size_t)row * HID;
    __shared__ float red[256];
    float ss = 0.f;
    for (int i = tid; i < HID; i += 256) { float f = xr[i]; ss += f * f; }
    red[tid] = ss;
    __syncthreads();
    for (int ofs = 128; ofs > 0; ofs >>= 1) {
        if (tid < ofs) red[tid] += red[tid + ofs];
        __syncthreads();
    }
    float rstd = rsqrtf(red[0] / (float)HID + 1e-5f);
    for (int i = tid; i < HID; i += 256)
        out[(size_t)row * HID + i] = xr[i] * rstd * scale[i];
}

// ---------------- GEMM (textbook 16x16 LDS tile, f32) ----------------------
// C[M,N] = A[M,K] @ B[N,K]^T + bias (+ residual). C may alias residual
// (element-wise read-before-write by the same thread).
__global__ __launch_bounds__(256) void gemm16(
    const float* __restrict__ A, const float* __restrict__ B,
    const float* __restrict__ bias, const float* residual,
    float* C, int M, int N, int K)
{
    __shared__ float As[16][17];
    __shared__ float Bs[16][17];
    const int tx = threadIdx.x, ty = threadIdx.y;
    const int row = blockIdx.y * 16 + ty;
    const int col = blockIdx.x * 16 + tx;
    int bn = blockIdx.x * 16 + ty;
    if (bn >= N) bn = N - 1;
    float acc = 0.f;
    for (int k0 = 0; k0 < K; k0 += 16) {
        As[ty][tx] = A[(size_t)row * K + k0 + tx];
        Bs[ty][tx] = B[(size_t)bn * K + k0 + tx];
        __syncthreads();
        #pragma unroll
        for (int kk = 0; kk < 16; kk++) acc += As[ty][kk] * Bs[tx][kk];
        __syncthreads();
    }
    if (col < N) {
        float v = acc + bias[col];
        if (residual) v += residual[(size_t)row * N + col];
        C[(size_t)row * N + col] = v;
    }
}

// ---------------- RoPE (YaRN-style NTK), scalar, f32 -----------------------
__global__ __launch_bounds__(256) void rope_naive(float* __restrict__ qkv)
{
    int idx = blockIdx.x * 256 + threadIdx.x;  // T*(NH+KV)*32
    int d = idx & 31;
    int rest = idx >> 5;
    int head = rest % (NH + KV);
    int tok = rest / (NH + KV);

    const float TWO_PI = 6.2831853071795864f;
    float fd = (float)d;
    float freq = powf(150000.0f, fd * (1.0f / 32.0f));
    float interpolation = 1.0f / (32.0f * freq);
    float extrapolation = 1.0f / freq;
    float lnb = logf(150000.0f);
    float low  = 32.0f * logf(4096.0f / (32.0f * TWO_PI)) / lnb;
    float high = 32.0f * logf(4096.0f / TWO_PI) / lnb;
    float ramp = (fd - low) / (high - low);
    ramp = fminf(fmaxf(ramp, 0.0f), 1.0f);
    float mask = 1.0f - ramp;
    float inv_freq = interpolation * (1.0f - mask) + extrapolation * mask;
    float conc = 0.1f * logf(32.0f) + 1.0f;
    float ang = (float)tok * inv_freq;
    float s = sinf(ang) * conc;
    float c = cosf(ang) * conc;

    size_t base = (head < NH)
        ? (size_t)tok * QKV_DIM + head * HD
        : (size_t)tok * QKV_DIM + NH * HD + (head - NH) * HD;
    float x1 = qkv[base + d];
    float x2 = qkv[base + 32 + d];
    qkv[base + d]      = x1 * c - x2 * s;
    qkv[base + 32 + d] = x2 * c + x1 * s;
}

// ---------------- Attention (naive, materialized scores per (t,h)) ---------
__global__ __launch_bounds__(256) void attn_naive(
    const float* __restrict__ qkv, float* __restrict__ o)
{
    const int t = blockIdx.x;
    const int h = blockIdx.y;
    const int g = h >> 3;
    const int tid = threadIdx.x;

    __shared__ float sc[T_TOK];
    __shared__ float red[256];
    __shared__ float qsh[HD];

    if (tid < HD) qsh[tid] = qkv[(size_t)t * QKV_DIM + h * HD + tid];
    __syncthreads();

    for (int s = tid; s <= t; s += 256) {
        const float* kr = qkv + (size_t)s * QKV_DIM + NH * HD + g * HD;
        float dot = 0.f;
        #pragma unroll
        for (int d = 0; d < HD; d++) dot += qsh[d] * kr[d];
        sc[s] = dot * 0.125f;
    }
    __syncthreads();

    float mx = -1e30f;
    for (int s = tid; s <= t; s += 256) mx = fmaxf(mx, sc[s]);
    red[tid] = mx;
    __syncthreads();
    for (int ofs = 128; ofs > 0; ofs >>= 1) {
        if (tid < ofs) red[tid] = fmaxf(red[tid], red[tid + ofs]);
        __syncthreads();
    }
    mx = red[0];
    __syncthreads();

    float sum = 0.f;
    for (int s = tid; s <= t; s += 256) {
        float p = expf(sc[s] - mx);
        sc[s] = p;
        sum += p;
    }
    red[tid] = sum;
    __syncthreads();
    for (int ofs = 128; ofs > 0; ofs >>= 1) {
        if (tid < ofs) red[tid] += red[tid + ofs];
        __syncthreads();
    }
    float denom = red[0];
    __syncthreads();

    const int d = tid & 63;
    const int part = tid >> 6;
    float acc = 0.f;
    for (int s = part; s <= t; s += 4)
        acc += sc[s] * qkv[(size_t)s * QKV_DIM + NH * HD + KV * HD + g * HD + d];
    red[tid] = acc;
    __syncthreads();
    if (part == 0) {
        float ov = (red[d] + red[64 + d] + red[128 + d] + red[192 + d]) / denom;
        o[(size_t)t * O_DIM + h * HD + d] = ov;
    }
}

// ---------------- gated activation -----------------------------------------
__global__ __launch_bounds__(256) void act_naive(
    const float* __restrict__ u, float* __restrict__ act)
{
    int i = blockIdx.x * 256 + threadIdx.x;
    if (i >= T_TOK * INTER) return;
    int row = i / INTER, c = i % INTER;
    float gt  = u[(size_t)row * (2 * INTER) + 2 * c];
    float lin = u[(size_t)row * (2 * INTER) + 2 * c + 1];
    gt = fminf(gt, 7.0f);
    lin = fminf(fmaxf(lin, -7.0f), 7.0f);
    float sg = 1.0f / (1.0f + expf(-1.702f * gt));
    act[i] = gt * sg * (lin + 1.0f);
}

extern "C" void kernel_launch(void* const* d_in, const int* in_sizes, int n_in,
                              void* d_out, int out_size, void* d_ws, size_t ws_size,
                              hipStream_t stream)
{
    const float* x               = (const float*)d_in[0];
    const float* attn_norm_scale = (const float*)d_in[1];
    const float* wqkv            = (const float*)d_in[2];
    const float* bqkv            = (const float*)d_in[3];
    const float* wout            = (const float*)d_in[4];
    const float* bout            = (const float*)d_in[5];
    const float* mlp_norm_scale  = (const float*)d_in[6];
    const float* w1              = (const float*)d_in[7];
    const float* b1              = (const float*)d_in[8];
    const float* w2              = (const float*)d_in[9];
    const float* b2              = (const float*)d_in[10];
    float* out = (float*)d_out;

    // ws layout (f32, peak 49.5 MB): [qkv 20.97MB][ob 16.78MB][scr 11.80MB]
    // u (23.6MB) aliases qkv + front of ob (both dead by then).
    // residual stream h lives in d_out.
    char* ws = (char*)d_ws;
    const size_t qkv_b = (size_t)T_TOK * QKV_DIM * 4;
    const size_t ob_b  = (size_t)T_TOK * O_DIM * 4;
    float* qkv = (float*)ws;
    float* ob  = (float*)(ws + qkv_b);
    float* scr = (float*)(ws + qkv_b + ob_b);
    float* u   = qkv;

    dim3 blk(16, 16);

    rmsnorm_naive<<<T_TOK, 256, 0, stream>>>(x, attn_norm_scale, scr);
    gemm16<<<dim3(QKV_DIM / 16, T_TOK / 16), blk, 0, stream>>>(
        scr, wqkv, bqkv, nullptr, qkv, T_TOK, QKV_DIM, HID);
    rope_naive<<<(T_TOK * (NH + KV) * 32) / 256, 256, 0, stream>>>(qkv);
    attn_naive<<<dim3(T_TOK, NH), 256, 0, stream>>>(qkv, ob);
    gemm16<<<dim3(HID / 16, T_TOK / 16), blk, 0, stream>>>(
        ob, wout, bout, x, out, T_TOK, HID, O_DIM);
    rmsnorm_naive<<<T_TOK, 256, 0, stream>>>(out, mlp_norm_scale, scr);
    gemm16<<<dim3((2 * INTER) / 16, T_TOK / 16), blk, 0, stream>>>(
        scr, w1, b1, nullptr, u, T_TOK, 2 * INTER, HID);
    act_naive<<<(T_TOK * INTER + 255) / 256, 256, 0, stream>>>(u, scr);
    gemm16<<<dim3(HID / 16, T_TOK / 16), blk, 0, stream>>>(
        scr, w2, b2, out, out, T_TOK, HID, INTER);
}

// Round 6
// 796.456 us; speedup vs baseline: 11.8438x; 11.8438x over previous
//
#include <hip/hip_runtime.h>

typedef unsigned short ushort_t;
typedef unsigned int uint_t;
typedef __bf16 bf16x8 __attribute__((ext_vector_type(8)));
typedef float floatx4 __attribute__((ext_vector_type(4)));

#define T_TOK 1024
#define HID 2880
#define NH 64
#define KV 8
#define HD 64
#define INTER 2880
#define QKV_DIM 5120   // HD*(NH+2*KV)
#define O_DIM 4096     // NH*HD

__device__ __forceinline__ float b2f(ushort_t u) {
    uint_t i = ((uint_t)u) << 16;
    return __builtin_bit_cast(float, i);
}
__device__ __forceinline__ ushort_t f2b(float f) {
    uint_t i = __builtin_bit_cast(uint_t, f);
    uint_t r = i + 0x7FFFu + ((i >> 16) & 1u);
    return (ushort_t)(r >> 16);
}
__device__ __forceinline__ uint4 ld16(const void* p) { uint4 v; __builtin_memcpy(&v, p, 16); return v; }
__device__ __forceinline__ void st16(void* p, uint4 v) { __builtin_memcpy(p, &v, 16); }
__device__ __forceinline__ float4 ld16f(const void* p) { float4 v; __builtin_memcpy(&v, p, 16); return v; }
__device__ __forceinline__ bf16x8 ldfrag(const void* p) { bf16x8 v; __builtin_memcpy(&v, p, 16); return v; }
__device__ __forceinline__ void cvt8st(void* lds, float4 a, float4 b) {
    ushort_t o[8] = {f2b(a.x), f2b(a.y), f2b(a.z), f2b(a.w),
                     f2b(b.x), f2b(b.y), f2b(b.z), f2b(b.w)};
    __builtin_memcpy(lds, o, 16);
}

// ---------------- RMSNorm: f32 in -> bf16 out ------------------------------
__global__ __launch_bounds__(256) void rmsnorm_f2b(
    const float* __restrict__ x, const float* __restrict__ scale,
    ushort_t* __restrict__ out)
{
    const int row = blockIdx.x;
    const int tid = threadIdx.x;
    const float* xr = x + (size_t)row * HID;
    float ss = 0.f;
    for (int i = tid; i < HID / 4; i += 256) {
        float4 v = ld16f(xr + i * 4);
        ss += v.x * v.x + v.y * v.y + v.z * v.z + v.w * v.w;
    }
    #pragma unroll
    for (int m = 32; m >= 1; m >>= 1) ss += __shfl_xor(ss, m, 64);
    __shared__ float red[4];
    if ((tid & 63) == 0) red[tid >> 6] = ss;
    __syncthreads();
    float rstd = rsqrtf((red[0] + red[1] + red[2] + red[3]) / (float)HID + 1e-5f);
    for (int i = tid; i < HID / 8; i += 256) {
        float4 a = ld16f(xr + i * 8);
        float4 b = ld16f(xr + i * 8 + 4);
        float4 sa = ld16f(scale + i * 8);
        float4 sb = ld16f(scale + i * 8 + 4);
        cvt8st(out + (size_t)row * HID + i * 8,
               make_float4(a.x * rstd * sa.x, a.y * rstd * sa.y, a.z * rstd * sa.z, a.w * rstd * sa.w),
               make_float4(b.x * rstd * sb.x, b.y * rstd * sb.y, b.z * rstd * sb.z, b.w * rstd * sb.w));
    }
}

// ---------------- GEMM: C[M,N] = A_bf16[M,K] @ B_f32[N,K]^T + bias ---------
// 128x128 tile, 4 waves (2x2 of 64x64), BK=32. Weights converted f32->bf16
// during staging. Output f32 (out_f32=1, optional f32 residual, may alias C
// element-wise) or bf16 (out_f32=0).
__global__ __launch_bounds__(256) void gemm_bt(
    const ushort_t* __restrict__ A, const float* __restrict__ B,
    const float* __restrict__ bias, const float* residual,
    void* C, int out_f32, int M, int N, int K)
{
    __shared__ ushort_t As[128 * 32];
    __shared__ ushort_t Bs[128 * 32];
    const int tid = threadIdx.x;
    const int m0 = blockIdx.y * 128;
    const int n0 = blockIdx.x * 128;
    const int lane = tid & 63, wave = tid >> 6;
    const int wm = (wave >> 1) * 64, wn = (wave & 1) * 64;
    const int l15 = lane & 15, quad = lane >> 4;

    floatx4 acc[4][4] = {};
    const int nk = K / 32;
    for (int kt = 0; kt < nk; ++kt) {
        const int k0 = kt * 32;
        #pragma unroll
        for (int i = 0; i < 2; i++) {
            int c = tid + 256 * i;
            int row = c >> 2;
            int col = (c & 3) * 8;
            st16(&As[c * 8], ld16(A + (size_t)(m0 + row) * K + k0 + col));
            int brow = n0 + row; if (brow >= N) brow = N - 1;
            const float* bp = B + (size_t)brow * K + k0 + col;
            cvt8st(&Bs[c * 8], ld16f(bp), ld16f(bp + 4));
        }
        __syncthreads();
        bf16x8 af[4], bf[4];
        #pragma unroll
        for (int i = 0; i < 4; i++)
            af[i] = ldfrag(&As[(wm + i * 16 + l15) * 32 + quad * 8]);
        #pragma unroll
        for (int j = 0; j < 4; j++)
            bf[j] = ldfrag(&Bs[(wn + j * 16 + l15) * 32 + quad * 8]);
        #pragma unroll
        for (int i = 0; i < 4; i++)
            #pragma unroll
            for (int j = 0; j < 4; j++)
                acc[i][j] = __builtin_amdgcn_mfma_f32_16x16x32_bf16(af[i], bf[j], acc[i][j], 0, 0, 0);
        __syncthreads();
    }
    // epilogue: C layout col=lane&15, row=quad*4+r
    #pragma unroll
    for (int i = 0; i < 4; i++) {
        int row = m0 + wm + i * 16 + quad * 4;
        #pragma unroll
        for (int j = 0; j < 4; j++) {
            int col = n0 + wn + j * 16 + l15;
            if (col < N) {
                float bv = bias[col];
                #pragma unroll
                for (int r = 0; r < 4; r++) {
                    float v = acc[i][j][r] + bv;
                    if (residual) v += residual[(size_t)(row + r) * N + col];
                    if (out_f32) ((float*)C)[(size_t)(row + r) * N + col] = v;
                    else ((ushort_t*)C)[(size_t)(row + r) * N + col] = f2b(v);
                }
            }
        }
    }
}

// ---------------- RoPE (YaRN-style NTK) on bf16 qkv ------------------------
__global__ __launch_bounds__(256) void rope_kernel(ushort_t* __restrict__ qkv)
{
    int idx = blockIdx.x * 256 + threadIdx.x;  // T*(NH+KV)*32
    int d = idx & 31;
    int rest = idx >> 5;
    int head = rest % (NH + KV);
    int tok = rest / (NH + KV);

    const float TWO_PI = 6.2831853071795864f;
    float fd = (float)d;
    float freq = powf(150000.0f, fd * (1.0f / 32.0f));
    float interpolation = 1.0f / (32.0f * freq);
    float extrapolation = 1.0f / freq;
    float lnb = logf(150000.0f);
    float low  = 32.0f * logf(4096.0f / (32.0f * TWO_PI)) / lnb;
    float high = 32.0f * logf(4096.0f / TWO_PI) / lnb;
    float ramp = (fd - low) / (high - low);
    ramp = fminf(fmaxf(ramp, 0.0f), 1.0f);
    float mask = 1.0f - ramp;
    float inv_freq = interpolation * (1.0f - mask) + extrapolation * mask;
    float conc = 0.1f * logf(32.0f) + 1.0f;
    float ang = (float)tok * inv_freq;
    float s = sinf(ang) * conc;
    float c = cosf(ang) * conc;

    size_t base = (head < NH)
        ? (size_t)tok * QKV_DIM + head * HD
        : (size_t)tok * QKV_DIM + NH * HD + (head - NH) * HD;
    float x1 = b2f(qkv[base + d]);
    float x2 = b2f(qkv[base + 32 + d]);
    qkv[base + d]      = f2b(x1 * c - x2 * s);
    qkv[base + 32 + d] = f2b(x2 * c + x1 * s);
}

// ---------------- Flash attention: causal GQA, one (head, 64-row Q tile) ---
__global__ __launch_bounds__(256) void attn_kernel(
    const ushort_t* __restrict__ qkv, ushort_t* __restrict__ o)
{
    const int qt = blockIdx.x;   // 0..15
    const int h  = blockIdx.y;   // 0..63
    const int g  = h >> 3;       // kv head
    const int tid = threadIdx.x;
    const int lane = tid & 63, wave = tid >> 6;
    const int l15 = lane & 15, quad = lane >> 4;

    __shared__ ushort_t Ks[64 * 72];      // K rows, padded stride 72
    __shared__ ushort_t Vt[64 * 72];      // V transposed: Vt[d][s]
    __shared__ ushort_t Ps[4][16 * 72];   // wave-private P

    bf16x8 qf[2];
    const int qrow = qt * 64 + wave * 16 + l15;
    #pragma unroll
    for (int c = 0; c < 2; c++)
        qf[c] = ldfrag(&qkv[(size_t)qrow * QKV_DIM + h * HD + quad * 8 + 32 * c]);

    floatx4 ofrag[4] = {};
    float mrow[4], lrow[4];
    #pragma unroll
    for (int r = 0; r < 4; r++) { mrow[r] = -1e30f; lrow[r] = 0.f; }

    for (int kt = 0; kt <= qt; ++kt) {
        {   // stage K (row-major, padded) and V (transposed)
            int row = tid >> 2;
            int seg = (tid & 3) * 16;
            size_t sb = (size_t)(kt * 64 + row) * QKV_DIM + NH * HD + g * HD;
            st16(&Ks[row * 72 + seg],     ld16(&qkv[sb + seg]));
            st16(&Ks[row * 72 + seg + 8], ld16(&qkv[sb + seg + 8]));
            uint4 v0 = ld16(&qkv[sb + KV * HD + seg]);
            uint4 v1 = ld16(&qkv[sb + KV * HD + seg + 8]);
            uint_t w0[4] = {v0.x, v0.y, v0.z, v0.w};
            uint_t w1[4] = {v1.x, v1.y, v1.z, v1.w};
            #pragma unroll
            for (int e = 0; e < 8; e++) {
                ushort_t s0 = (e & 1) ? (ushort_t)(w0[e >> 1] >> 16) : (ushort_t)(w0[e >> 1] & 0xffffu);
                ushort_t s1 = (e & 1) ? (ushort_t)(w1[e >> 1] >> 16) : (ushort_t)(w1[e >> 1] & 0xffffu);
                Vt[(seg + e) * 72 + row]     = s0;
                Vt[(seg + 8 + e) * 72 + row] = s1;
            }
        }
        __syncthreads();

        // S = Q K^T (scaled); C layout row=quad*4+r (query), col=lane&15 (key)
        floatx4 sf[4];
        #pragma unroll
        for (int j = 0; j < 4; j++) {
            floatx4 z = {};
            #pragma unroll
            for (int c = 0; c < 2; c++) {
                bf16x8 kf = ldfrag(&Ks[(j * 16 + l15) * 72 + quad * 8 + 32 * c]);
                z = __builtin_amdgcn_mfma_f32_16x16x32_bf16(qf[c], kf, z, 0, 0, 0);
            }
            sf[j] = z;
        }
        const int qg = qt * 64 + wave * 16 + quad * 4;
        const int kgb = kt * 64 + l15;
        float rowmax[4];
        #pragma unroll
        for (int r = 0; r < 4; r++) rowmax[r] = -1e30f;
        #pragma unroll
        for (int j = 0; j < 4; j++)
            #pragma unroll
            for (int r = 0; r < 4; r++) {
                float v = sf[j][r] * 0.125f;
                if (kgb + j * 16 > qg + r) v = -1e30f;
                sf[j][r] = v;
                rowmax[r] = fmaxf(rowmax[r], v);
            }
        #pragma unroll
        for (int r = 0; r < 4; r++)
            #pragma unroll
            for (int m = 1; m < 16; m <<= 1)
                rowmax[r] = fmaxf(rowmax[r], __shfl_xor(rowmax[r], m, 64));
        float alpha[4], rowsum[4];
        #pragma unroll
        for (int r = 0; r < 4; r++) {
            float mnew = fmaxf(mrow[r], rowmax[r]);
            alpha[r] = __expf(mrow[r] - mnew);
            mrow[r] = mnew;
            rowsum[r] = 0.f;
        }
        #pragma unroll
        for (int j = 0; j < 4; j++)
            #pragma unroll
            for (int r = 0; r < 4; r++) {
                float p = __expf(sf[j][r] - mrow[r]);
                rowsum[r] += p;
                Ps[wave][(quad * 4 + r) * 72 + j * 16 + l15] = f2b(p);
            }
        #pragma unroll
        for (int r = 0; r < 4; r++) {
            #pragma unroll
            for (int m = 1; m < 16; m <<= 1)
                rowsum[r] += __shfl_xor(rowsum[r], m, 64);
            lrow[r] = lrow[r] * alpha[r] + rowsum[r];
        }
        #pragma unroll
        for (int j = 0; j < 4; j++)
            #pragma unroll
            for (int r = 0; r < 4; r++)
                ofrag[j][r] *= alpha[r];
        __syncthreads();   // Ps visible before A-layout reads
        #pragma unroll
        for (int c = 0; c < 2; c++) {
            bf16x8 pf = ldfrag(&Ps[wave][l15 * 72 + quad * 8 + 32 * c]);
            #pragma unroll
            for (int j = 0; j < 4; j++) {
                bf16x8 vf = ldfrag(&Vt[(j * 16 + l15) * 72 + quad * 8 + 32 * c]);
                ofrag[j] = __builtin_amdgcn_mfma_f32_16x16x32_bf16(pf, vf, ofrag[j], 0, 0, 0);
            }
        }
        __syncthreads();
    }
    #pragma unroll
    for (int j = 0; j < 4; j++)
        #pragma unroll
        for (int r = 0; r < 4; r++) {
            int row = qt * 64 + wave * 16 + quad * 4 + r;
            int col = h * HD + j * 16 + l15;
            o[(size_t)row * O_DIM + col] = f2b(ofrag[j][r] / lrow[r]);
        }
}

// ---------------- gated activation: u bf16 [T,2I] -> ac bf16 [T,I] ---------
__global__ __launch_bounds__(256) void act_kernel(
    const ushort_t* __restrict__ u, ushort_t* __restrict__ act)
{
    int i = blockIdx.x * 256 + threadIdx.x;
    if (i >= T_TOK * INTER) return;
    int row = i / INTER, c = i % INTER;
    uint_t v; __builtin_memcpy(&v, u + (size_t)row * (2 * INTER) + 2 * c, 4);
    float gt  = b2f((ushort_t)(v & 0xffffu));
    float lin = b2f((ushort_t)(v >> 16));
    gt = fminf(gt, 7.0f);
    lin = fminf(fmaxf(lin, -7.0f), 7.0f);
    float sg = 1.0f / (1.0f + __expf(-1.702f * gt));
    act[i] = f2b(gt * sg * (lin + 1.0f));
}

extern "C" void kernel_launch(void* const* d_in, const int* in_sizes, int n_in,
                              void* d_out, int out_size, void* d_ws, size_t ws_size,
                              hipStream_t stream)
{
    const float* x               = (const float*)d_in[0];
    const float* attn_norm_scale = (const float*)d_in[1];
    const float* wqkv            = (const float*)d_in[2];
    const float* bqkv            = (const float*)d_in[3];
    const float* wout            = (const float*)d_in[4];
    const float* bout            = (const float*)d_in[5];
    const float* mlp_norm_scale  = (const float*)d_in[6];
    const float* w1              = (const float*)d_in[7];
    const float* b1              = (const float*)d_in[8];
    const float* w2              = (const float*)d_in[9];
    const float* b2              = (const float*)d_in[10];
    float* out = (float*)d_out;

    // ws (bf16 buffers, total 42.5 MB < proven 49.5):
    // [t 5.9][qkv 10.49][ob 8.39][u 11.8][ac 5.9]; h lives in d_out (f32).
    char* ws = (char*)d_ws;
    ushort_t* t   = (ushort_t*)ws;                               // T*HID
    ushort_t* qkv = (ushort_t*)(ws + (size_t)T_TOK * HID * 2);
    ushort_t* ob  = (ushort_t*)(ws + (size_t)T_TOK * (HID + QKV_DIM) * 2);
    ushort_t* u   = (ushort_t*)(ws + (size_t)T_TOK * (HID + QKV_DIM + O_DIM) * 2);
    ushort_t* ac  = (ushort_t*)(ws + (size_t)T_TOK * (HID + QKV_DIM + O_DIM + 2 * INTER) * 2);

    rmsnorm_f2b<<<T_TOK, 256, 0, stream>>>(x, attn_norm_scale, t);
    gemm_bt<<<dim3(QKV_DIM / 128, T_TOK / 128), 256, 0, stream>>>(
        t, wqkv, bqkv, nullptr, qkv, 0, T_TOK, QKV_DIM, HID);
    rope_kernel<<<(T_TOK * (NH + KV) * 32) / 256, 256, 0, stream>>>(qkv);
    attn_kernel<<<dim3(T_TOK / 64, NH), 256, 0, stream>>>(qkv, ob);
    gemm_bt<<<dim3((HID + 127) / 128, T_TOK / 128), 256, 0, stream>>>(
        ob, wout, bout, x, out, 1, T_TOK, HID, O_DIM);           // h -> d_out
    rmsnorm_f2b<<<T_TOK, 256, 0, stream>>>(out, mlp_norm_scale, t);
    gemm_bt<<<dim3((2 * INTER) / 128, T_TOK / 128), 256, 0, stream>>>(
        t, w1, b1, nullptr, u, 0, T_TOK, 2 * INTER, HID);
    act_kernel<<<(T_TOK * INTER + 255) / 256, 256, 0, stream>>>(u, ac);
    gemm_bt<<<dim3((HID + 127) / 128, T_TOK / 128), 256, 0, stream>>>(
        ac, w2, b2, out, out, 1, T_TOK, HID, INTER);             // in-place residual
}